// Round 9
// baseline (39.022 us; speedup 1.0000x reference)
//
#include <hip/hip_runtime.h>
#include <cstdint>

static constexpr int BATCH = 64;
static constexpr int NPB   = 512 * 512;   // elements per batch
static constexpr int NFB   = 2048;        // fixed fine bins in sigmoid space [0,1]

// d_ws layout in 32-bit words (header is PBLK-independent):
static constexpr int W_BMIN = 0;        // up to 2048 blocks * 4 per-wave mins
static constexpr int W_BMAX = 8192;
static constexpr int W_PART = 16384;    // NBLK x 2048 words (u16-packed 4096 counts)

__device__ __forceinline__ float sigmoidf(float v) {  // precise: pmin/pmax only
  if (v >= 0.0f) return 1.0f / (1.0f + expf(-v));
  float e = expf(v);
  return e / (1.0f + e);
}
__device__ __forceinline__ float fsig(float v) {      // fast: per-element binning only
  return __builtin_amdgcn_rcpf(1.0f + __expf(-v));
}

// Pass: ONE visit of x and tg. Per block: per-wave min/max of x + fixed-grid joint
// histogram (2048 sigmoid bins x 2 classes) in ONE 16 KiB LDS replica; u16-packed
// partial out. 16.4 KiB LDS + ~52 VGPR -> 8 blocks/CU resident.
template <int PBLK>
__global__ __launch_bounds__(256) void k_pass(const float* __restrict__ x,
                                              const float* __restrict__ tg,
                                              uint32_t* __restrict__ ws,
                                              float* __restrict__ out) {
  constexpr int ELB  = NPB / PBLK;        // elements per block
  constexpr int ITER = ELB / 4 / 256;     // float4 iterations per thread
  __shared__ uint32_t h[2 * NFB];         // 4096 counters = 16 KiB
  const int t = threadIdx.x;
  const int g = blockIdx.x;
  if (g == 0 && t == 0) out[0] = 0.0f;    // re-zeroed every launch before finalize
#pragma unroll
  for (int j = 0; j < 4; ++j)
    reinterpret_cast<uint4*>(h)[t + j * 256] = uint4{0u, 0u, 0u, 0u};
  __syncthreads();

  const int b = g / PBLK;
  const int blk = g % PBLK;
  const size_t base = (size_t)b * NPB + (size_t)blk * ELB;
  const float4* px = reinterpret_cast<const float4*>(x + base);
  const float4* pt = reinterpret_cast<const float4*>(tg + base);

  float mn = INFINITY, mx = -INFINITY;
#pragma unroll 4
  for (int i = 0; i < ITER; ++i) {
    float4 v = px[i * 256 + t];
    float4 w = pt[i * 256 + t];
    mn = fminf(mn, fminf(fminf(v.x, v.y), fminf(v.z, v.w)));
    mx = fmaxf(mx, fmaxf(fmaxf(v.x, v.y), fmaxf(v.z, v.w)));
#define PUT(a, c) { int idx = (int)(fsig(a) * 2048.0f);                   \
                    idx = idx > 2047 ? 2047 : idx;                        \
                    idx += ((c) > 0.5f) ? 2048 : 0;                       \
                    atomicAdd(&h[idx], 1u); }
    PUT(v.x, w.x) PUT(v.y, w.y) PUT(v.z, w.z) PUT(v.w, w.w)
#undef PUT
  }
  // per-wave min/max straight to global (no LDS needed)
  for (int off = 32; off; off >>= 1) {
    mn = fminf(mn, __shfl_down(mn, off));
    mx = fmaxf(mx, __shfl_down(mx, off));
  }
  if ((t & 63) == 0) {
    float* wsf = reinterpret_cast<float*>(ws);
    wsf[W_BMIN + g * 4 + (t >> 6)] = mn;
    wsf[W_BMAX + g * 4 + (t >> 6)] = mx;
  }
  __syncthreads();
  // pack 2 u16 counts per word (count <= ELB fits u16 for PBLK>=8), plain store
  uint32_t* gp = ws + W_PART + (size_t)g * NFB;
#pragma unroll
  for (int j = 0; j < 8; ++j) {
    const int w = t + j * 256;            // word index 0..2047
    gp[w] = h[2 * w] | (h[2 * w + 1] << 16);
  }
}

// Finalize: one block per batch. Merge PBLK partials -> fine hist; exact pmin/pmax;
// remap fine bins to the reference 512-halfbin grid; Otsu argmax; suffix counts; IoU.
template <int PBLK>
__global__ __launch_bounds__(256) void k_finalize(uint32_t* __restrict__ ws,
                                                  float* __restrict__ out) {
  __shared__ uint32_t fj[2 * NFB];        // 4096 fine counts (16 KiB)
  __shared__ uint32_t h256[256];
  __shared__ uint32_t w1s[256];
  __shared__ float s1s[256];
  __shared__ float vv[256];
  __shared__ int vi[256];
  __shared__ unsigned long long redL[256];
  __shared__ float sPmin, sScale, sBinw;
  const int b = blockIdx.x;
  const int t = threadIdx.x;
  const float* wsf = reinterpret_cast<const float*>(ws);

  // merge PBLK u16-packed partials (coalesced: consecutive t -> consecutive words)
#pragma unroll
  for (int j = 0; j < 8; ++j) {
    const int w = t + j * 256;
    uint32_t a0 = 0, a1 = 0;
    for (int p = 0; p < PBLK; ++p) {
      const uint32_t v = ws[W_PART + (size_t)(b * PBLK + p) * NFB + w];
      a0 += v & 0xFFFFu;
      a1 += v >> 16;
    }
    fj[2 * w] = a0;
    fj[2 * w + 1] = a1;
  }
  h256[t] = 0u;
  // batch min/max over PBLK*4 per-wave values (wave 0 only)
  if (t < 64) {
    float mnv = INFINITY, mxv = -INFINITY;
    for (int i = t; i < PBLK * 4; i += 64) {
      mnv = fminf(mnv, wsf[W_BMIN + b * PBLK * 4 + i]);
      mxv = fmaxf(mxv, wsf[W_BMAX + b * PBLK * 4 + i]);
    }
    for (int off = 32; off; off >>= 1) {
      mnv = fminf(mnv, __shfl_down(mnv, off));
      mxv = fmaxf(mxv, __shfl_down(mxv, off));
    }
    if (t == 0) {
      const float pmin = sigmoidf(mnv);
      const float pmax = sigmoidf(mxv);
      const float span = pmax - pmin;
      sPmin = pmin;
      sScale = (span > 0.0f) ? (512.0f / span) : 0.0f;   // halfbin scale (=2*scale256)
      sBinw = span * (1.0f / 256.0f);                    // span/NBINS (pow2, exact)
    }
  }
  __syncthreads();
  const float pmin = sPmin, scale = sScale, binw = sBinw;

  // fine -> 512-halfbin remap via bin midpoint; build 256-bin Otsu hist
#define CIDX(k) ({ const float rep = ((float)(k) + 0.5f) * (1.0f / 2048.0f);  \
                   int ci = (int)((rep - pmin) * scale);                      \
                   ci = ci < 0 ? 0 : (ci > 511 ? 511 : ci); ci; })
#pragma unroll
  for (int j = 0; j < 8; ++j) {
    const int w = t + j * 256;
    const int i0 = 2 * w, i1 = 2 * w + 1;
    const int k0 = i0 & (NFB - 1), k1 = i1 & (NFB - 1);
    if (fj[i0]) atomicAdd(&h256[CIDX(k0) >> 1], fj[i0]);
    if (fj[i1]) atomicAdd(&h256[CIDX(k1) >> 1], fj[i1]);
  }
  __syncthreads();

  // Otsu over 256 bins (reference arithmetic)
  const uint32_t hk = h256[t];
  const float ck = pmin + ((float)t + 0.5f) * binw;     // centers[t]
  w1s[t] = hk;
  s1s[t] = (float)hk * ck;
  for (int off = 1; off < 256; off <<= 1) {             // Hillis-Steele scans
    __syncthreads();
    uint32_t wp = (t >= off) ? w1s[t - off] : 0u;
    float    sp = (t >= off) ? s1s[t - off] : 0.0f;
    __syncthreads();
    w1s[t] += wp; s1s[t] += sp;
  }
  __syncthreads();
  const uint32_t totW = w1s[255];
  const float totS = s1s[255];
  float v = -INFINITY;
  if (t < 255 && w1s[t] > 0u && totW > w1s[t]) {
    const float w1f = (float)w1s[t];
    const float w2f = (float)(totW - w1s[t]);
    const float m1 = s1s[t] / w1f;
    const float m2 = (totS - s1s[t]) / w2f;
    const float d = m1 - m2;
    v = (w1f * w2f) * (d * d);
  }
  vv[t] = v; vi[t] = t;
  for (int s = 128; s; s >>= 1) {          // argmax, first-occurrence tie-break
    __syncthreads();
    if (t < s) {
      const float vb = vv[t + s]; const int ib = vi[t + s];
      if (vb > vv[t] || (vb == vv[t] && ib < vi[t])) { vv[t] = vb; vi[t] = ib; }
    }
  }
  __syncthreads();
  const int J = 2 * vi[0] + 1;             // threshold = halfbin boundary index

  // suffix counts over fine bins whose halfbin index >= J
  uint32_t nb_p = 0, ni_p = 0, nt_p = 0;
#pragma unroll
  for (int j = 0; j < 8; ++j) {
    const int w = t + j * 256;
#pragma unroll
    for (int e = 0; e < 2; ++e) {
      const int idx = 2 * w + e;
      const uint32_t cnt = fj[idx];
      const int cls = idx >> 11;           // 0..1 (NFB=2048)
      const int k = idx & (NFB - 1);
      nt_p += cls ? cnt : 0u;
      if (CIDX(k) >= J) { nb_p += cnt; ni_p += cls ? cnt : 0u; }
    }
  }
#undef CIDX
  redL[t] = (unsigned long long)nb_p | ((unsigned long long)ni_p << 20) | ((unsigned long long)nt_p << 40);
  for (int s = 128; s; s >>= 1) {
    __syncthreads();
    if (t < s) redL[t] += redL[t + s];
  }
  __syncthreads();
  if (t == 0) {
    const unsigned long long P = redL[0];
    const float nb = (float)(uint32_t)(P & 0xFFFFFu);
    const float ni = (float)(uint32_t)((P >> 20) & 0xFFFFFu);
    const float nt = (float)(uint32_t)((P >> 40) & 0xFFFFFu);
    const float uni = nb + nt - ni;
    const float iou = (ni + 1.0f) / (uni + 1.0f);
    atomicAdd(out, iou * (1.0f / 64.0f));
  }
}

template <int PBLK>
static void launch_all(const float* x, const float* tg, uint32_t* ws, float* out,
                       hipStream_t stream) {
  hipLaunchKernelGGL((k_pass<PBLK>),     dim3(BATCH * PBLK), dim3(256), 0, stream, x, tg, ws, out);
  hipLaunchKernelGGL((k_finalize<PBLK>), dim3(BATCH),        dim3(256), 0, stream, ws, out);
}

extern "C" void kernel_launch(void* const* d_in, const int* in_sizes, int n_in,
                              void* d_out, int out_size, void* d_ws, size_t ws_size,
                              hipStream_t stream) {
  const float* x  = (const float*)d_in[0];   // logits (64,1,512,512)
  const float* tg = (const float*)d_in[1];   // target (64,1,512,512)
  uint32_t* ws = (uint32_t*)d_ws;
  float* out = (float*)d_out;

  const size_t need32 = (size_t)(W_PART + BATCH * 32 * NFB) * 4;   // ~16.8 MB
  const size_t need16 = (size_t)(W_PART + BATCH * 16 * NFB) * 4;   // ~8.5 MB
  if (ws_size >= need32)      launch_all<32>(x, tg, ws, out, stream);
  else if (ws_size >= need16) launch_all<16>(x, tg, ws, out, stream);
  else                        launch_all<8>(x, tg, ws, out, stream);
}

// Round 10
// 35.050 us; speedup vs baseline: 1.1133x; 1.1133x over previous
//
#include <hip/hip_runtime.h>
#include <cstdint>

static constexpr int BATCH = 64;
static constexpr int NPB   = 512 * 512;   // elements per batch
static constexpr int NFB   = 2048;        // fixed fine bins in sigmoid space [0,1]
static constexpr int PBLK  = 16;          // pass blocks per batch (1024 total)
static constexpr int ELB   = NPB / PBLK;  // 16384 elements per block

// d_ws layout in 32-bit words (~8.4 MB, fully rewritten every launch):
static constexpr int W_BMIN = 0;          // 1024 blocks x 4 per-wave mins
static constexpr int W_BMAX = 4096;
static constexpr int W_PART = 8192;       // 1024 blocks x 2048 words (tot|pos<<16 per bin)

__device__ __forceinline__ float sigmoidf(float v) {  // precise: pmin/pmax only
  if (v >= 0.0f) return 1.0f / (1.0f + expf(-v));
  float e = expf(v);
  return e / (1.0f + e);
}
__device__ __forceinline__ float fsig(float v) {      // fast: per-element binning only
  return __builtin_amdgcn_rcpf(1.0f + __expf(-v));
}

// Pass: ONE visit of x and tg. Per block: per-wave min/max of x + fixed-grid hist
// (2048 bins; one u32 per bin carries total|pos<<16) in 2 LDS replicas (8 KiB each,
// one per wave-pair). Non-returning workgroup-scope atomics. u32 partial flush.
__global__ __launch_bounds__(256) void k_pass(const float* __restrict__ x,
                                              const float* __restrict__ tg,
                                              uint32_t* __restrict__ ws,
                                              float* __restrict__ out) {
  constexpr int ITER = ELB / 4 / 256;     // 16 float4 iterations per thread
  __shared__ uint32_t h[2 * NFB];         // 2 replicas x 2048 counters = 16 KiB
  const int t = threadIdx.x;
  const int g = blockIdx.x;
  if (g == 0 && t == 0) out[0] = 0.0f;    // re-zeroed every launch before finalize
#pragma unroll
  for (int j = 0; j < 4; ++j)
    reinterpret_cast<uint4*>(h)[t + j * 256] = uint4{0u, 0u, 0u, 0u};
  __syncthreads();

  const int b = g >> 4;
  const int blk = g & 15;
  const size_t base = (size_t)b * NPB + (size_t)blk * ELB;
  const float4* px = reinterpret_cast<const float4*>(x + base);
  const float4* pt = reinterpret_cast<const float4*>(tg + base);
  const uint32_t woff = (uint32_t)(t >> 7) << 11;   // wave-pair replica (0 or 2048)

  float mn = INFINITY, mx = -INFINITY;
#pragma unroll 4
  for (int i = 0; i < ITER; ++i) {
    float4 v = px[i * 256 + t];
    float4 w = pt[i * 256 + t];
    mn = fminf(mn, fminf(fminf(v.x, v.y), fminf(v.z, v.w)));
    mx = fmaxf(mx, fmaxf(fmaxf(v.x, v.y), fmaxf(v.z, v.w)));
#define PUT(a, c) { int idx = (int)(fsig(a) * 2048.0f);                        \
                    idx = idx > 2047 ? 2047 : idx;                             \
                    const uint32_t val = ((c) > 0.5f) ? 0x10001u : 1u;         \
                    (void)__hip_atomic_fetch_add(&h[woff + idx], val,          \
                        __ATOMIC_RELAXED, __HIP_MEMORY_SCOPE_WORKGROUP); }
    PUT(v.x, w.x) PUT(v.y, w.y) PUT(v.z, w.z) PUT(v.w, w.w)
#undef PUT
  }
  // per-wave min/max straight to global
  for (int off = 32; off; off >>= 1) {
    mn = fminf(mn, __shfl_down(mn, off));
    mx = fmaxf(mx, __shfl_down(mx, off));
  }
  if ((t & 63) == 0) {
    float* wsf = reinterpret_cast<float*>(ws);
    wsf[W_BMIN + g * 4 + (t >> 6)] = mn;
    wsf[W_BMAX + g * 4 + (t >> 6)] = mx;
  }
  __syncthreads();
  // merge 2 replicas (u16 fields add independently: tot,pos <= 16384) -> plain store
  uint32_t* gp = ws + W_PART + (size_t)g * NFB;
#pragma unroll
  for (int j = 0; j < 8; ++j) {
    const int w = t + j * 256;            // bin 0..2047
    gp[w] = h[w] + h[w + 2048];
  }
}

// Finalize: one block per batch. Merge 16 partials -> tot/pos fine hists; exact
// pmin/pmax; remap fine bins to the 512-halfbin reference grid; Otsu; suffix; IoU.
__global__ __launch_bounds__(256) void k_finalize(uint32_t* __restrict__ ws,
                                                  float* __restrict__ out) {
  __shared__ uint32_t tot[NFB];           // 8 KiB
  __shared__ uint32_t pos[NFB];           // 8 KiB
  __shared__ uint32_t h256[256];
  __shared__ uint32_t w1s[256];
  __shared__ float s1s[256];
  __shared__ float vv[256];
  __shared__ int vi[256];
  __shared__ unsigned long long redL[256];
  __shared__ float sPmin, sScale, sBinw;
  const int b = blockIdx.x;
  const int t = threadIdx.x;
  const float* wsf = reinterpret_cast<const float*>(ws);

  // merge 16 partials (coalesced: consecutive t -> consecutive words)
#pragma unroll
  for (int j = 0; j < 8; ++j) {
    const int w = t + j * 256;
    uint32_t at = 0, ap = 0;
#pragma unroll
    for (int p = 0; p < PBLK; ++p) {
      const uint32_t v = ws[W_PART + (size_t)(b * PBLK + p) * NFB + w];
      at += v & 0xFFFFu;
      ap += v >> 16;
    }
    tot[w] = at;
    pos[w] = ap;
  }
  h256[t] = 0u;
  // batch min/max over PBLK*4 per-wave values (wave 0 only)
  if (t < 64) {
    float mnv = INFINITY, mxv = -INFINITY;
    for (int i = t; i < PBLK * 4; i += 64) {
      mnv = fminf(mnv, wsf[W_BMIN + b * PBLK * 4 + i]);
      mxv = fmaxf(mxv, wsf[W_BMAX + b * PBLK * 4 + i]);
    }
    for (int off = 32; off; off >>= 1) {
      mnv = fminf(mnv, __shfl_down(mnv, off));
      mxv = fmaxf(mxv, __shfl_down(mxv, off));
    }
    if (t == 0) {
      const float pmin = sigmoidf(mnv);
      const float pmax = sigmoidf(mxv);
      const float span = pmax - pmin;
      sPmin = pmin;
      sScale = (span > 0.0f) ? (512.0f / span) : 0.0f;   // halfbin scale (=2*scale256)
      sBinw = span * (1.0f / 256.0f);                    // span/NBINS (pow2, exact)
    }
  }
  __syncthreads();
  const float pmin = sPmin, scale = sScale, binw = sBinw;

  // fine -> 512-halfbin remap via bin midpoint; build 256-bin Otsu hist
#define CIDX(k) ({ const float rep = ((float)(k) + 0.5f) * (1.0f / 2048.0f);  \
                   int ci = (int)((rep - pmin) * scale);                      \
                   ci = ci < 0 ? 0 : (ci > 511 ? 511 : ci); ci; })
#pragma unroll
  for (int j = 0; j < 8; ++j) {
    const int k = t + j * 256;
    if (tot[k]) atomicAdd(&h256[CIDX(k) >> 1], tot[k]);
  }
  __syncthreads();

  // Otsu over 256 bins (reference arithmetic)
  const uint32_t hk = h256[t];
  const float ck = pmin + ((float)t + 0.5f) * binw;     // centers[t]
  w1s[t] = hk;
  s1s[t] = (float)hk * ck;
  for (int off = 1; off < 256; off <<= 1) {             // Hillis-Steele scans
    __syncthreads();
    uint32_t wp = (t >= off) ? w1s[t - off] : 0u;
    float    sp = (t >= off) ? s1s[t - off] : 0.0f;
    __syncthreads();
    w1s[t] += wp; s1s[t] += sp;
  }
  __syncthreads();
  const uint32_t totW = w1s[255];
  const float totS = s1s[255];
  float v = -INFINITY;
  if (t < 255 && w1s[t] > 0u && totW > w1s[t]) {
    const float w1f = (float)w1s[t];
    const float w2f = (float)(totW - w1s[t]);
    const float m1 = s1s[t] / w1f;
    const float m2 = (totS - s1s[t]) / w2f;
    const float d = m1 - m2;
    v = (w1f * w2f) * (d * d);
  }
  vv[t] = v; vi[t] = t;
  for (int s = 128; s; s >>= 1) {          // argmax, first-occurrence tie-break
    __syncthreads();
    if (t < s) {
      const float vb = vv[t + s]; const int ib = vi[t + s];
      if (vb > vv[t] || (vb == vv[t] && ib < vi[t])) { vv[t] = vb; vi[t] = ib; }
    }
  }
  __syncthreads();
  const int J = 2 * vi[0] + 1;             // threshold = halfbin boundary index

  // suffix counts over fine bins whose halfbin index >= J; nt = sum(pos)
  uint32_t nb_p = 0, ni_p = 0, nt_p = 0;
#pragma unroll
  for (int j = 0; j < 8; ++j) {
    const int k = t + j * 256;
    const uint32_t ct = tot[k], cp = pos[k];
    nt_p += cp;
    if (CIDX(k) >= J) { nb_p += ct; ni_p += cp; }
  }
#undef CIDX
  redL[t] = (unsigned long long)nb_p | ((unsigned long long)ni_p << 20) | ((unsigned long long)nt_p << 40);
  for (int s = 128; s; s >>= 1) {
    __syncthreads();
    if (t < s) redL[t] += redL[t + s];
  }
  __syncthreads();
  if (t == 0) {
    const unsigned long long P = redL[0];
    const float nb = (float)(uint32_t)(P & 0xFFFFFu);
    const float ni = (float)(uint32_t)((P >> 20) & 0xFFFFFu);
    const float nt = (float)(uint32_t)((P >> 40) & 0xFFFFFu);
    const float uni = nb + nt - ni;
    const float iou = (ni + 1.0f) / (uni + 1.0f);
    atomicAdd(out, iou * (1.0f / 64.0f));
  }
}

extern "C" void kernel_launch(void* const* d_in, const int* in_sizes, int n_in,
                              void* d_out, int out_size, void* d_ws, size_t ws_size,
                              hipStream_t stream) {
  const float* x  = (const float*)d_in[0];   // logits (64,1,512,512)
  const float* tg = (const float*)d_in[1];   // target (64,1,512,512)
  uint32_t* ws = (uint32_t*)d_ws;
  float* out = (float*)d_out;

  hipLaunchKernelGGL(k_pass,     dim3(BATCH * PBLK), dim3(256), 0, stream, x, tg, ws, out);
  hipLaunchKernelGGL(k_finalize, dim3(BATCH),        dim3(256), 0, stream, ws, out);
}